// Round 1
// baseline (773.217 us; speedup 1.0000x reference)
//
#include <hip/hip_runtime.h>

#define DIM 192
#define YZ (DIM * DIM)
#define NB 2
#define PADW 4
#define NCH 5
#define TY 32
#define TZ 32
#define TYH (TY + 2 * PADW)   // 40
#define TZH (TZ + 2 * PADW)   // 40
#define LDP 41                // padded LDS row stride (odd -> conflict-free)
#define CST 33                // padded C row stride

__global__ void ncc_init(double* acc) { *acc = 0.0; }

// Pass 1: sliding-window box sum along X (stride YZ) of the 5 products.
// Threads: z (192). Blocks: (x-chunks, y, b).
__global__ __launch_bounds__(192) void ncc_pass1(
    const float* __restrict__ I, const float* __restrict__ J,
    float* __restrict__ S, int x_start, int x_cnt) {
  const int z = threadIdx.x;
  const int y = blockIdx.y;
  const int b = blockIdx.z;
  const int xc0 = blockIdx.x * 24;
  if (xc0 >= x_cnt) return;
  const int xend = (xc0 + 24 < x_cnt) ? (xc0 + 24) : x_cnt;
  const size_t base = (size_t)b * DIM * YZ + (size_t)y * DIM + z;
  const size_t chstride = (size_t)NB * x_cnt * YZ;

  float s1 = 0.f, s2 = 0.f, s3 = 0.f, s4 = 0.f, s5 = 0.f;
  const int xg0 = x_start + xc0;
  // prime window [xg0-4, xg0+3]
  #pragma unroll
  for (int k = -PADW; k < PADW; ++k) {
    int xx = xg0 + k;
    if (xx >= 0 && xx < DIM) {
      float a = I[base + (size_t)xx * YZ];
      float c = J[base + (size_t)xx * YZ];
      s1 += a; s2 += c; s3 += a * a; s4 += c * c; s5 += a * c;
    }
  }
  for (int xr = xc0; xr < xend; ++xr) {
    const int xg = x_start + xr;
    const int xa = xg + PADW;
    if (xa < DIM) {
      float a = I[base + (size_t)xa * YZ];
      float c = J[base + (size_t)xa * YZ];
      s1 += a; s2 += c; s3 += a * a; s4 += c * c; s5 += a * c;
    }
    const size_t ob = (size_t)b * x_cnt * YZ + (size_t)xr * YZ + (size_t)y * DIM + z;
    S[ob]                = s1;
    S[ob +     chstride] = s2;
    S[ob + 2 * chstride] = s3;
    S[ob + 3 * chstride] = s4;
    S[ob + 4 * chstride] = s5;
    const int xs = xg - PADW;
    if (xs >= 0) {   // re-load (L1/L2 hit) instead of a runtime-indexed ring buffer
      float a = I[base + (size_t)xs * YZ];
      float c = J[base + (size_t)xs * YZ];
      s1 -= a; s2 -= c; s3 -= a * a; s4 -= c * c; s5 -= a * c;
    }
  }
}

// Pass 2: per (b, x, 32x32 yz-tile): LDS-staged Y-box + Z-box (sliding windows),
// then NCC pointwise + block reduction -> one f64 atomicAdd.
__global__ __launch_bounds__(256) void ncc_pass2(
    const float* __restrict__ S, double* __restrict__ acc, int x_cnt) {
  __shared__ float sm[NCH * TYH * LDP + NCH * TY * LDP];  // 59 KB -> 2 blocks/CU
  __shared__ double red[4];
  float* Abuf = sm;                       // [ch][yy<40][zz], stride LDP
  float* Bbuf = sm + NCH * TYH * LDP;     // [ch][yo<32][zz], stride LDP
  float* Cbuf = sm;                       // reuses A region: [ch][yo<32][zo], stride CST

  const int tid = threadIdx.x;
  const int xr = blockIdx.x;
  const int ty = blockIdx.y / 6;
  const int tz = blockIdx.y % 6;
  const int b  = blockIdx.z;
  const int y0 = ty * TY - PADW;
  const int z0 = tz * TZ - PADW;

  // stage A (halo tile, zero-padded)
  for (int i = tid; i < NCH * TYH * TZH; i += 256) {
    int ch = i / (TYH * TZH);
    int r  = i - ch * (TYH * TZH);
    int yy = r / TZH;
    int zz = r - yy * TZH;
    int y = y0 + yy, z = z0 + zz;
    float v = 0.f;
    if ((unsigned)y < DIM && (unsigned)z < DIM)
      v = S[(size_t)(ch * NB + b) * x_cnt * YZ + (size_t)xr * YZ + (size_t)y * DIM + z];
    Abuf[(ch * TYH + yy) * LDP + zz] = v;
  }
  __syncthreads();

  // Y-box: 200 columns (ch, zz), sliding along y
  if (tid < NCH * TZH) {
    int ch = tid / TZH, zz = tid - (tid / TZH) * TZH;
    float* col  = Abuf + ch * TYH * LDP + zz;
    float* bcol = Bbuf + ch * TY  * LDP + zz;
    float s = 0.f;
    #pragma unroll
    for (int k = 0; k < 2 * PADW; ++k) s += col[k * LDP];
    for (int yo = 0; yo < TY; ++yo) {
      s += col[(yo + 2 * PADW) * LDP];
      bcol[yo * LDP] = s;
      s -= col[yo * LDP];
    }
  }
  __syncthreads();

  // Z-box: 160 rows (ch, yo), sliding along z; writes alias the dead A region
  if (tid < NCH * TY) {
    int ch = tid / TY, yo = tid - (tid / TY) * TY;
    float* row  = Bbuf + (ch * TY + yo) * LDP;
    float* crow = Cbuf + (ch * TY + yo) * CST;
    float s = 0.f;
    #pragma unroll
    for (int k = 0; k < 2 * PADW; ++k) s += row[k];
    for (int zo = 0; zo < TZ; ++zo) {
      s += row[zo + 2 * PADW];
      crow[zo] = s;
      s -= row[zo];
    }
  }
  __syncthreads();

  // NCC pointwise + reduce
  float part = 0.f;
  const float inv = 1.0f / 729.0f;
  for (int p = tid; p < TY * TZ; p += 256) {
    int yo = p / TZ, zo = p - (p / TZ) * TZ;
    float i_s = Cbuf[(0 * TY + yo) * CST + zo];
    float j_s = Cbuf[(1 * TY + yo) * CST + zo];
    float i2  = Cbuf[(2 * TY + yo) * CST + zo];
    float j2  = Cbuf[(3 * TY + yo) * CST + zo];
    float ij  = Cbuf[(4 * TY + yo) * CST + zo];
    float cross = ij - i_s * j_s * inv;
    float iv    = i2 - i_s * i_s * inv;
    float jv    = j2 - j_s * j_s * inv;
    part += cross * cross / (iv * jv + 1e-5f);
  }
  double d = (double)part;
  #pragma unroll
  for (int off = 32; off > 0; off >>= 1) d += __shfl_down(d, off, 64);
  if ((tid & 63) == 0) red[tid >> 6] = d;
  __syncthreads();
  if (tid == 0) atomicAdd(acc, red[0] + red[1] + red[2] + red[3]);
}

__global__ void ncc_fin(const double* __restrict__ acc, float* __restrict__ out) {
  out[0] = (float)(-(*acc) / (double)((size_t)NB * DIM * DIM * DIM));
}

extern "C" void kernel_launch(void* const* d_in, const int* in_sizes, int n_in,
                              void* d_out, int out_size, void* d_ws, size_t ws_size,
                              hipStream_t stream) {
  const float* I = (const float*)d_in[0];
  const float* J = (const float*)d_in[1];
  float* out = (float*)d_out;
  double* acc = (double*)d_ws;
  float* S = (float*)((char*)d_ws + 256);

  // slab size along x sized to available workspace (full volume = 283 MB + 256 B)
  const size_t perx = (size_t)NCH * NB * YZ * sizeof(float);  // 1,474,560 B per x-slice
  size_t cap = (ws_size > 256) ? (ws_size - 256) / perx : 0;
  int Sx = (int)((cap < (size_t)DIM) ? cap : (size_t)DIM);
  if (Sx < 1) Sx = 1;

  ncc_init<<<dim3(1), dim3(1), 0, stream>>>(acc);
  for (int x0 = 0; x0 < DIM; x0 += Sx) {
    int cnt = (DIM - x0 < Sx) ? (DIM - x0) : Sx;
    dim3 g1((unsigned)((cnt + 23) / 24), DIM, NB);
    ncc_pass1<<<g1, dim3(192), 0, stream>>>(I, J, S, x0, cnt);
    dim3 g2((unsigned)cnt, 36, NB);
    ncc_pass2<<<g2, dim3(256), 0, stream>>>(S, acc, cnt);
  }
  ncc_fin<<<dim3(1), dim3(1), 0, stream>>>(acc, out);
}

// Round 2
// 743.038 us; speedup vs baseline: 1.0406x; 1.0406x over previous
//
#include <hip/hip_runtime.h>

#define DIM 192
#define YZ (DIM * DIM)
#define NB 2
#define PADW 4
#define NCH 5
#define CH1 16               // x-chunk length per thread, pass 1
#define TILE 32
#define TH 40                // TILE + 2*PADW
#define LDP 41               // padded LDS stride (A, B)
#define CST 33               // padded LDS stride (C)
#define STRIP 8

__device__ inline float4 f4add(float4 a, float4 b) { return make_float4(a.x+b.x, a.y+b.y, a.z+b.z, a.w+b.w); }
__device__ inline float4 f4sub(float4 a, float4 b) { return make_float4(a.x-b.x, a.y-b.y, a.z-b.z, a.w-b.w); }
__device__ inline float4 f4mul(float4 a, float4 b) { return make_float4(a.x*b.x, a.y*b.y, a.z*b.z, a.w*b.w); }

__global__ void ncc_init(double* acc) { *acc = 0.0; }

// Pass 1: sliding-window box sum along X of the 5 products, float4 along z.
// Threads 192 = 48 z-quads x 4 y. Blocks: (x-chunks, 48 y-groups, b).
__global__ __launch_bounds__(192) void ncc_pass1(
    const float* __restrict__ I, const float* __restrict__ J,
    float* __restrict__ S, int x_start, int x_cnt) {
  const int z4 = threadIdx.x % 48;
  const int y  = blockIdx.y * 4 + threadIdx.x / 48;
  const int b  = blockIdx.z;
  const int xc0 = blockIdx.x * CH1;
  if (xc0 >= x_cnt) return;
  const int xend = (xc0 + CH1 < x_cnt) ? (xc0 + CH1) : x_cnt;

  const float4* I4 = (const float4*)I;
  const float4* J4 = (const float4*)J;
  float4* S4 = (float4*)S;
  const size_t base4 = ((size_t)b * DIM * YZ + (size_t)y * DIM) / 4 + z4;
  const size_t xs4 = YZ / 4;                       // x-slice stride in float4
  const size_t ch4 = (size_t)NB * x_cnt * xs4;     // channel stride in float4

  float4 s1 = make_float4(0,0,0,0), s2 = s1, s3 = s1, s4 = s1, s5 = s1;
  const int xg0 = x_start + xc0;
  #pragma unroll
  for (int k = -PADW; k < PADW; ++k) {
    int xx = xg0 + k;
    if (xx >= 0 && xx < DIM) {
      float4 a = I4[base4 + (size_t)xx * xs4];
      float4 c = J4[base4 + (size_t)xx * xs4];
      s1 = f4add(s1, a); s2 = f4add(s2, c);
      s3 = f4add(s3, f4mul(a, a)); s4 = f4add(s4, f4mul(c, c)); s5 = f4add(s5, f4mul(a, c));
    }
  }
  for (int xr = xc0; xr < xend; ++xr) {
    const int xg = x_start + xr;
    const int xa = xg + PADW;
    if (xa < DIM) {
      float4 a = I4[base4 + (size_t)xa * xs4];
      float4 c = J4[base4 + (size_t)xa * xs4];
      s1 = f4add(s1, a); s2 = f4add(s2, c);
      s3 = f4add(s3, f4mul(a, a)); s4 = f4add(s4, f4mul(c, c)); s5 = f4add(s5, f4mul(a, c));
    }
    const size_t ob4 = ((size_t)b * x_cnt + xr) * xs4 + ((size_t)y * DIM) / 4 + z4;
    S4[ob4]           = s1;
    S4[ob4 +     ch4] = s2;
    S4[ob4 + 2 * ch4] = s3;
    S4[ob4 + 3 * ch4] = s4;
    S4[ob4 + 4 * ch4] = s5;
    const int xs = xg - PADW;
    if (xs >= 0) {   // trailing edge: re-load (L2 hit) instead of a ring buffer
      float4 a = I4[base4 + (size_t)xs * xs4];
      float4 c = J4[base4 + (size_t)xs * xs4];
      s1 = f4sub(s1, a); s2 = f4sub(s2, c);
      s3 = f4sub(s3, f4mul(a, a)); s4 = f4sub(s4, f4mul(c, c)); s5 = f4sub(s5, f4mul(a, c));
    }
  }
}

// Pass 2: per (b, x, 32x32 yz-tile): LDS Y-box + Z-box via parallel 8-strips,
// then NCC pointwise + block reduction -> one f64 atomicAdd.
__global__ __launch_bounds__(256) void ncc_pass2(
    const float* __restrict__ S, double* __restrict__ acc, int x_cnt) {
  __shared__ float sm[NCH * TH * LDP + NCH * TILE * LDP];  // 59 KB
  __shared__ double red[4];
  float* A = sm;                           // [ch][yy<40][zz<40], stride LDP
  float* B = sm + NCH * TH * LDP;          // [ch][yo<32][zz<40], stride LDP
  float* C = sm;                           // aliases dead A: [ch][yo<32][zo<32], stride CST

  const int tid = threadIdx.x;
  const int xr = blockIdx.x;
  const int ty = blockIdx.y / 6;
  const int tz = blockIdx.y % 6;
  const int b  = blockIdx.z;
  const int y0 = ty * TILE - PADW;
  const int z0 = tz * TILE - PADW;

  // stage A (halo tile, zero-padded)
  for (int i = tid; i < NCH * TH * TH; i += 256) {
    int ch = i / (TH * TH);
    int r  = i - ch * (TH * TH);
    int yy = r / TH;
    int zz = r - yy * TH;
    int y = y0 + yy, z = z0 + zz;
    float v = 0.f;
    if ((unsigned)y < DIM && (unsigned)z < DIM)
      v = S[((size_t)ch * NB + b) * x_cnt * YZ + (size_t)xr * YZ + (size_t)y * DIM + z];
    A[(ch * TH + yy) * LDP + zz] = v;
  }
  __syncthreads();

  // Y-box: 800 parallel strip-tasks (ch, zz, 8-y strip)
  for (int t = tid; t < NCH * TH * 4; t += 256) {
    int ch = t / (TH * 4);
    int r  = t - ch * (TH * 4);
    int zz = r % TH;
    int ys = (r / TH) * STRIP;
    const float* col = A + ch * TH * LDP + zz;
    float* bp = B + ch * TILE * LDP + zz;
    float s = 0.f;
    #pragma unroll
    for (int k = 0; k < STRIP; ++k) s += col[(ys + k) * LDP];
    #pragma unroll
    for (int yo = 0; yo < STRIP; ++yo) {
      s += col[(ys + yo + STRIP) * LDP];
      bp[(ys + yo) * LDP] = s;
      s -= col[(ys + yo) * LDP];
    }
  }
  __syncthreads();

  // Z-box: 640 parallel strip-tasks (ch, yo, 8-z strip); writes alias dead A
  for (int t = tid; t < NCH * TILE * 4; t += 256) {
    int ch  = t / (TILE * 4);
    int r   = t - ch * (TILE * 4);
    int zsi = r & 3;
    int yo  = r >> 2;
    const float* row = B + (ch * TILE + yo) * LDP;
    float* cp = C + (ch * TILE + yo) * CST;
    int zs = zsi * STRIP;
    float s = 0.f;
    #pragma unroll
    for (int k = 0; k < STRIP; ++k) s += row[zs + k];
    #pragma unroll
    for (int zo = 0; zo < STRIP; ++zo) {
      s += row[zs + zo + STRIP];
      cp[zs + zo] = s;
      s -= row[zs + zo];
    }
  }
  __syncthreads();

  // NCC pointwise + reduce
  float part = 0.f;
  const float inv = 1.0f / 729.0f;
  for (int p = tid; p < TILE * TILE; p += 256) {
    int yo = p / TILE, zo = p - (p / TILE) * TILE;
    float i_s = C[(0 * TILE + yo) * CST + zo];
    float j_s = C[(1 * TILE + yo) * CST + zo];
    float i2  = C[(2 * TILE + yo) * CST + zo];
    float j2  = C[(3 * TILE + yo) * CST + zo];
    float ij  = C[(4 * TILE + yo) * CST + zo];
    float cross = ij - i_s * j_s * inv;
    float iv    = i2 - i_s * i_s * inv;
    float jv    = j2 - j_s * j_s * inv;
    part += cross * cross / (iv * jv + 1e-5f);
  }
  double d = (double)part;
  #pragma unroll
  for (int off = 32; off > 0; off >>= 1) d += __shfl_down(d, off, 64);
  if ((tid & 63) == 0) red[tid >> 6] = d;
  __syncthreads();
  if (tid == 0) atomicAdd(acc, red[0] + red[1] + red[2] + red[3]);
}

__global__ void ncc_fin(const double* __restrict__ acc, float* __restrict__ out) {
  out[0] = (float)(-(*acc) / (double)((size_t)NB * DIM * DIM * DIM));
}

extern "C" void kernel_launch(void* const* d_in, const int* in_sizes, int n_in,
                              void* d_out, int out_size, void* d_ws, size_t ws_size,
                              hipStream_t stream) {
  const float* I = (const float*)d_in[0];
  const float* J = (const float*)d_in[1];
  float* out = (float*)d_out;
  double* acc = (double*)d_ws;
  float* S = (float*)((char*)d_ws + 256);

  const size_t perx = (size_t)NCH * NB * YZ * sizeof(float);  // bytes per x-slice of S
  size_t cap = (ws_size > 256) ? (ws_size - 256) / perx : 0;
  int Sx = (int)((cap < (size_t)DIM) ? cap : (size_t)DIM);
  if (Sx < 1) Sx = 1;

  ncc_init<<<dim3(1), dim3(1), 0, stream>>>(acc);
  for (int x0 = 0; x0 < DIM; x0 += Sx) {
    int cnt = (DIM - x0 < Sx) ? (DIM - x0) : Sx;
    dim3 g1((unsigned)((cnt + CH1 - 1) / CH1), 48, NB);
    ncc_pass1<<<g1, dim3(192), 0, stream>>>(I, J, S, x0, cnt);
    dim3 g2((unsigned)cnt, 36, NB);
    ncc_pass2<<<g2, dim3(256), 0, stream>>>(S, acc, cnt);
  }
  ncc_fin<<<dim3(1), dim3(1), 0, stream>>>(acc, out);
}

// Round 5
// 248.498 us; speedup vs baseline: 3.1116x; 2.9901x over previous
//
#include <hip/hip_runtime.h>

#define DIM 192
#define YZ (DIM * DIM)          // 36864
#define VOL (DIM * YZ)          // 7077888
#define NB 2
#define PADW 4
#define TILE 32
#define TH 40                   // TILE + 2*PADW
#define SXP 44                  // Sx row stride: 44 floats = 176 B -> quads 16B-aligned
#define BPP 33                  // Bp row stride (odd -> conflict-free column reads)
#define XCH 24                  // x-chunk per block (192/24 = 8 chunks)
#define SX_CH (TH * SXP)        // 1760
#define BP_CH (TH * BPP)        // 1320
#define SX_SZ (5 * SX_CH)       // 8800 floats = 35.2 KB
#define BP_SZ (5 * BP_CH)       // 6600 floats = 26.4 KB

__device__ inline float4 f4add(float4 a, float4 b) { return make_float4(a.x+b.x, a.y+b.y, a.z+b.z, a.w+b.w); }
__device__ inline float4 f4sub(float4 a, float4 b) { return make_float4(a.x-b.x, a.y-b.y, a.z-b.z, a.w-b.w); }
__device__ inline float4 f4mul(float4 a, float4 b) { return make_float4(a.x*b.x, a.y*b.y, a.z*b.z, a.w*b.w); }

__global__ void ncc_init(double* acc) { *acc = 0.0; }

// One kernel: sliding X-box window in LDS (Sx, 5 channels over the 40x40 halo),
// per x-step Z-box (Sx->Bp) then Y-box+NCC into register partials.
__global__ __launch_bounds__(256) void ncc_fused(
    const float* __restrict__ I, const float* __restrict__ J,
    double* __restrict__ acc) {
  __shared__ float Sx[SX_SZ];   // running X-window sums, halo tile, 5 ch
  __shared__ float Bp[BP_SZ];   // Z-boxed (y-halo kept), 5 ch
  __shared__ double red[4];

  const int tid = threadIdx.x;
  const int xc0 = blockIdx.x * XCH;
  const int ty = blockIdx.y / 6, tz = blockIdx.y - 6 * (blockIdx.y / 6);
  const int b  = blockIdx.z;
  const int y0 = ty * TILE - PADW, z0 = tz * TILE - PADW;
  const float* Ib = I + (size_t)b * VOL;
  const float* Jb = J + (size_t)b * VOL;

  // ---- ph1 task geometry: 400 float4-tasks over the 40x40 halo (10 quads/row)
  const int q1i = tid + 256;
  const int yy0 = tid / 10,  zf0 = tid - 10 * (tid / 10);
  const int yy1 = q1i / 10,  zf1 = q1i - 10 * (q1i / 10);
  const int gy0 = y0 + yy0, gz0 = z0 + 4 * zf0;
  const int gy1 = y0 + yy1, gz1 = z0 + 4 * zf1;
  const bool v0 = ((unsigned)gy0 < DIM) && ((unsigned)gz0 < DIM);
  const bool v1 = (q1i < 400) && ((unsigned)gy1 < DIM) && ((unsigned)gz1 < DIM);
  const size_t gb0 = (size_t)gy0 * DIM + gz0;
  const size_t gb1 = (size_t)gy1 * DIM + gz1;
  const int la0 = yy0 * SXP + 4 * zf0;   // byte offset la*4 is 16B-aligned
  const int la1 = yy1 * SXP + 4 * zf1;

  for (int i = tid; i < SX_SZ; i += 256) Sx[i] = 0.f;
  __syncthreads();  // Sx zeroed before prime writes

  // ---- prime: window [xc0-4, xc0+4] accumulated in registers, one b128 write/ch
  auto prime_task = [&](bool v, size_t gb, int la) {
    if (!v) return;
    float4 s1 = make_float4(0,0,0,0), s2 = s1, s3 = s1, s4 = s1, s5 = s1;
    #pragma unroll
    for (int k = -PADW; k <= PADW; ++k) {
      int xx = xc0 + k;
      if ((unsigned)xx >= DIM) continue;
      float4 a = *(const float4*)(Ib + (size_t)xx * YZ + gb);
      float4 c = *(const float4*)(Jb + (size_t)xx * YZ + gb);
      s1 = f4add(s1, a); s2 = f4add(s2, c);
      s3 = f4add(s3, f4mul(a, a)); s4 = f4add(s4, f4mul(c, c)); s5 = f4add(s5, f4mul(a, c));
    }
    *(float4*)(Sx + 0*SX_CH + la) = s1;
    *(float4*)(Sx + 1*SX_CH + la) = s2;
    *(float4*)(Sx + 2*SX_CH + la) = s3;
    *(float4*)(Sx + 3*SX_CH + la) = s4;
    *(float4*)(Sx + 4*SX_CH + la) = s5;
  };
  prime_task(v0, gb0, la0);
  prime_task(v1, gb1, la1);
  __syncthreads();

  auto ph2_task = [&](int t) {  // Z-box: one half-row (6 b128 reads -> 16 outputs)
    const int half = t & 1, rid = t >> 1;
    const int ch = rid / TH, yy = rid - TH * (rid / TH);
    const float* srow = Sx + ch * SX_CH + yy * SXP + half * 16;
    float* brow = Bp + ch * BP_CH + yy * BPP + half * 16;
    float4 q[6];
    #pragma unroll
    for (int k = 0; k < 6; ++k) q[k] = *(const float4*)(srow + 4 * k);
    const float* s = (const float*)q;
    float w = s[0]+s[1]+s[2]+s[3]+s[4]+s[5]+s[6]+s[7];
    #pragma unroll
    for (int k = 0; k < 16; ++k) { w += s[k+8]; brow[k] = w; w -= s[k]; }
  };

  auto rmw_task = [&](bool v, float4 nA, float4 nC, float4 oA, float4 oC, int la) {
    if (!v) return;
    float4* p0 = (float4*)(Sx + 0*SX_CH + la);
    float4* p1 = (float4*)(Sx + 1*SX_CH + la);
    float4* p2 = (float4*)(Sx + 2*SX_CH + la);
    float4* p3 = (float4*)(Sx + 3*SX_CH + la);
    float4* p4 = (float4*)(Sx + 4*SX_CH + la);
    *p0 = f4add(*p0, f4sub(nA, oA));
    *p1 = f4add(*p1, f4sub(nC, oC));
    *p2 = f4add(*p2, f4sub(f4mul(nA, nA), f4mul(oA, oA)));
    *p3 = f4add(*p3, f4sub(f4mul(nC, nC), f4mul(oC, oC)));
    *p4 = f4add(*p4, f4sub(f4mul(nA, nC), f4mul(oA, oC)));
  };

  double dsum = 0.0;
  const int zo = tid & 31, yb = (tid >> 5) * 4;

  for (int xi = 0; xi < XCH; ++xi) {
    const int x = xc0 + xi;

    // ---- ph2: Z-box Sx -> Bp
    ph2_task(tid);
    if (tid + 256 < 400) ph2_task(tid + 256);
    __syncthreads();

    const bool haveNext = (xi + 1 < XCH);
    const int xa = x + PADW + 1;   // slice to add for x+1
    const int xs = x - PADW;       // slice to subtract for x+1
    const bool av = haveNext && ((unsigned)xa < DIM);
    const bool sv = haveNext && (xs >= 0);

    // ---- ph1-issue: global loads early (latency hides under ph3)
    float4 zf4 = make_float4(0,0,0,0);
    float4 nA0=zf4, nC0=zf4, oA0=zf4, oC0=zf4, nA1=zf4, nC1=zf4, oA1=zf4, oC1=zf4;
    if (v0) {
      if (av) { nA0 = *(const float4*)(Ib + (size_t)xa * YZ + gb0);
                nC0 = *(const float4*)(Jb + (size_t)xa * YZ + gb0); }
      if (sv) { oA0 = *(const float4*)(Ib + (size_t)xs * YZ + gb0);
                oC0 = *(const float4*)(Jb + (size_t)xs * YZ + gb0); }
    }
    if (v1) {
      if (av) { nA1 = *(const float4*)(Ib + (size_t)xa * YZ + gb1);
                nC1 = *(const float4*)(Jb + (size_t)xa * YZ + gb1); }
      if (sv) { oA1 = *(const float4*)(Ib + (size_t)xs * YZ + gb1);
                oC1 = *(const float4*)(Jb + (size_t)xs * YZ + gb1); }
    }

    // ---- ph3: Y-box + NCC for output x (register sliding windows)
    {
      float sm[5][4];
      #pragma unroll
      for (int ch = 0; ch < 5; ++ch) {
        const float* col = Bp + ch * BP_CH + zo;
        float v[12];
        #pragma unroll
        for (int k = 0; k < 12; ++k) v[k] = col[(yb + k) * BPP];
        float w = v[0]+v[1]+v[2]+v[3]+v[4]+v[5]+v[6]+v[7]+v[8];
        sm[ch][0] = w;
        #pragma unroll
        for (int r = 1; r < 4; ++r) { w += v[r+8]; w -= v[r-1]; sm[ch][r] = w; }
      }
      const float inv = 1.0f / 729.0f;
      float part = 0.f;
      #pragma unroll
      for (int r = 0; r < 4; ++r) {
        float isv = sm[0][r], jsv = sm[1][r], i2 = sm[2][r], j2 = sm[3][r], ij = sm[4][r];
        float cross = ij - isv * jsv * inv;
        float ivr   = i2 - isv * isv * inv;
        float jvr   = j2 - jsv * jsv * inv;
        part += cross * cross / (ivr * jvr + 1e-5f);
      }
      dsum += (double)part;
    }

    // ---- ph1-commit: RMW Sx for next x (each task owns its quad; no races)
    if (haveNext) {
      rmw_task(v0, nA0, nC0, oA0, oC0, la0);
      rmw_task(v1, nA1, nC1, oA1, oC1, la1);
    }
    __syncthreads();
  }

  // ---- block reduction -> one atomic
  #pragma unroll
  for (int off = 32; off > 0; off >>= 1) dsum += __shfl_down(dsum, off, 64);
  if ((tid & 63) == 0) red[tid >> 6] = dsum;
  __syncthreads();
  if (tid == 0) atomicAdd(acc, red[0] + red[1] + red[2] + red[3]);
}

__global__ void ncc_fin(const double* __restrict__ acc, float* __restrict__ out) {
  out[0] = (float)(-(*acc) / (double)((size_t)NB * VOL));
}

extern "C" void kernel_launch(void* const* d_in, const int* in_sizes, int n_in,
                              void* d_out, int out_size, void* d_ws, size_t ws_size,
                              hipStream_t stream) {
  const float* I = (const float*)d_in[0];
  const float* J = (const float*)d_in[1];
  float* out = (float*)d_out;
  double* acc = (double*)d_ws;

  ncc_init<<<dim3(1), dim3(1), 0, stream>>>(acc);
  dim3 grid(DIM / XCH, 36, NB);   // 8 x-chunks, 6x6 yz-tiles, 2 batch
  ncc_fused<<<grid, dim3(256), 0, stream>>>(I, J, acc);
  ncc_fin<<<dim3(1), dim3(1), 0, stream>>>(acc, out);
}